// Round 13
// baseline (2609.728 us; speedup 1.0000x reference)
//
#include <hip/hip_runtime.h>
#include <hip/hip_bf16.h>

// Problem dims
#define B_   512
#define WIN_ 128
#define D_   256
#define H_   512
#define O_   64
#define P_   64
#define K2H  1024   // 2H (q = [h|c])
#define KG   832    // gates GEMM K = O(64) + D(256) + H(512)
#define NG   2048   // 4*H gate dims
#define NSLN 320    // slab N: 256 (Wq) + 64 (y)

typedef __attribute__((ext_vector_type(8))) short bf16x8;
typedef __attribute__((ext_vector_type(4))) float f32x4;
using bf16 = __hip_bfloat16;

__device__ __forceinline__ float fast_tanh(float x){
    float e = __expf(2.f * x);
    return 1.f - __fdividef(2.f, e + 1.f);
}
__device__ __forceinline__ float fast_sig(float x){
    return __fdividef(1.f, 1.f + __expf(-x));
}
__device__ __forceinline__ float b_lo(unsigned int u){ return __uint_as_float(u << 16); }
__device__ __forceinline__ float b_hi(unsigned int u){ return __uint_as_float(u & 0xffff0000u); }
__device__ __forceinline__ short f2bs(float v){
    return (short)__builtin_bit_cast(unsigned short, __float2bfloat16(v));
}
__device__ __forceinline__ unsigned int pack2(float a, float b){
    unsigned short sa = __builtin_bit_cast(unsigned short, __float2bfloat16(a));
    unsigned short sb = __builtin_bit_cast(unsigned short, __float2bfloat16(b));
    return (unsigned int)sa | ((unsigned int)sb << 16);
}

// ---------------- prep: dtype conversions + weight packing ----------------
__global__ void k_prep(const float* __restrict__ x, const float* __restrict__ W,
                       const float* __restrict__ U, const float* __restrict__ W_ih,
                       const float* __restrict__ W_hh, const float* __restrict__ b_ih,
                       const float* __restrict__ b_hh, const float* __restrict__ Wd,
                       const float* __restrict__ Ws, const float* __restrict__ Wc,
                       bf16* __restrict__ x_bf, bf16* __restrict__ Wcomb,
                       bf16* __restrict__ Wsl, bf16* __restrict__ U_bf,
                       bf16* __restrict__ Wsc, float* __restrict__ bsum)
{
    const long NXv = (long)B_ * WIN_ * D_ / 8;    // vectorized x: 8 floats each
    const long NWC = (long)NG * KG;
    const long NSL = (long)8 * NSLN * 128;
    const long NU  = (long)D_ * D_;
    const long NWS = (long)K2H * D_;
    const long NB  = NG;
    const long total = NXv + NWC + NSL + NU + NWS + NB;
    for (long i = (long)blockIdx.x * blockDim.x + threadIdx.x; i < total;
         i += (long)gridDim.x * blockDim.x) {
        long j = i;
        if (j < NXv) {
            const float4* xp = (const float4*)x + j * 2;
            float4 a = xp[0], b = xp[1];
            bf16x8 v;
            v[0] = f2bs(a.x); v[1] = f2bs(a.y); v[2] = f2bs(a.z); v[3] = f2bs(a.w);
            v[4] = f2bs(b.x); v[5] = f2bs(b.y); v[6] = f2bs(b.z); v[7] = f2bs(b.w);
            *(bf16x8*)((short*)x_bf + j * 8) = v;
            continue;
        }
        j -= NXv;
        if (j < NWC) {      // [W_ih | W_hh] packed K=832
            long n = j / KG, k = j % KG;
            float v = (k < 320) ? W_ih[n * 320 + k] : W_hh[n * 512 + (k - 320)];
            Wcomb[j] = __float2bfloat16(v); continue;
        }
        j -= NWC;
        if (j < NSL) {      // K-slice 'by' of [W ; Wd] for slab partials
            long by = j / (NSLN * 128);
            long rem = j % (NSLN * 128);
            long n = rem / 128, k = rem % 128;
            float v;
            if (n < 256) v = (k < 64) ? W[n * K2H + by * 64 + k]
                                      : W[n * K2H + 512 + by * 64 + (k - 64)];
            else         v = (k < 64) ? Wd[(n - 256) * H_ + by * 64 + k] : 0.f;
            Wsl[j] = __float2bfloat16(v); continue;
        }
        j -= NSL;
        if (j < NU) { U_bf[j] = __float2bfloat16(U[j]); continue; }
        j -= NU;
        if (j < NWS) {      // [Ws;Wc]
            long n = j / D_, k = j % D_;
            float v = (n < 512) ? Ws[n * D_ + k] : Wc[(n - 512) * D_ + k];
            Wsc[j] = __float2bfloat16(v); continue;
        }
        j -= NWS;
        bsum[j] = b_ih[j] + b_hh[j];
    }
}

// ------- init (MFMA): x_last(512x256) @ Wsc^T(1024x256) -> h0 | c0 ---------
__global__ void __launch_bounds__(256) k_init2(const bf16* __restrict__ x_bf,
                       const bf16* __restrict__ Wsc, const float* __restrict__ bs,
                       const float* __restrict__ bc, bf16* __restrict__ q_buf,
                       bf16* __restrict__ A0, float* __restrict__ c_f32)
{
    int wave = threadIdx.x >> 6, lane = threadIdx.x & 63;
    int m0 = blockIdx.x * 16;
    int n0 = blockIdx.y * 64 + wave * 16;
    int r = lane & 15, ko = (lane >> 4) * 8, rj = (lane >> 4) * 4;
    const short* xp = (const short*)x_bf;
    const short* wp = (const short*)Wsc;
    f32x4 acc = {};
    #pragma unroll
    for (int k0 = 0; k0 < D_; k0 += 32) {
        bf16x8 a  = *(const bf16x8*)(xp + (long)(m0 + r) * (WIN_ * D_) + 127 * D_ + k0 + ko);
        bf16x8 bb = *(const bf16x8*)(wp + (long)(n0 + r) * D_ + k0 + ko);
        acc = __builtin_amdgcn_mfma_f32_16x16x32_bf16(a, bb, acc, 0, 0, 0);
    }
    int n = n0 + r;
    if (n0 < 512) {          // h0
        float bias = bs[n];
        #pragma unroll
        for (int j = 0; j < 4; ++j) {
            int b = m0 + rj + j;
            float hv = fast_tanh(acc[j] + bias);
            bf16 hb = __float2bfloat16(hv);
            q_buf[(long)b * K2H + n]   = hb;
            A0[(long)b * KG + 320 + n] = hb;
        }
    } else {                 // c0
        float bias = bc[n - 512];
        #pragma unroll
        for (int j = 0; j < 4; ++j) {
            int b = m0 + rj + j;
            float cv = fast_sig(acc[j] + bias);
            q_buf[(long)b * K2H + n]        = __float2bfloat16(cv);
            c_f32[(long)b * H_ + (n - 512)] = cv;
        }
    }
}

// ---------------- Uk[b] = U @ x[b]^T  (x-tile staged in LDS) ----------------
__global__ void __launch_bounds__(256) k_uk(const bf16* __restrict__ U_bf,
                    const bf16* __restrict__ x_bf, bf16* __restrict__ Uk)
{
    __shared__ __align__(16) short xs[64][264];
    int b  = blockIdx.y;
    int v0 = (blockIdx.x >> 1) * 64;
    int w0 = (blockIdx.x & 1) * 64;
    {   // stage x rows w0..w0+63 ; 64B-contiguous per 4 lanes, spread banks
        const short* xg = (const short*)x_bf + (long)b * (WIN_ * D_) + (long)w0 * D_;
        int row = threadIdx.x >> 2, c4 = (threadIdx.x & 3) * 8;
        #pragma unroll
        for (int i = 0; i < 8; ++i)
            *(bf16x8*)(&xs[row][c4 + i * 32]) = *(const bf16x8*)(xg + (long)row * D_ + c4 + i * 32);
    }
    __syncthreads();
    int lane = threadIdx.x & 63;
    int wave = threadIdx.x >> 6;
    int r  = lane & 15;
    int ko = (lane >> 4) * 8;
    const short* Up = (const short*)U_bf + (long)(v0 + wave * 16 + r) * D_;
    f32x4 acc[4] = {};
    #pragma unroll 2
    for (int k0 = 0; k0 < D_; k0 += 32) {
        bf16x8 a = *(const bf16x8*)(Up + k0 + ko);
        #pragma unroll
        for (int f = 0; f < 4; ++f) {
            bf16x8 bb = *(const bf16x8*)(&xs[f * 16 + r][k0 + ko]);
            acc[f] = __builtin_amdgcn_mfma_f32_16x16x32_bf16(a, bb, acc[f], 0, 0, 0);
        }
    }
    bf16* up = Uk + (long)b * (D_ * WIN_);
    int vbase = v0 + wave * 16 + (lane >> 4) * 4;
    #pragma unroll
    for (int f = 0; f < 4; ++f) {
        int w = w0 + f * 16 + r;
        #pragma unroll
        for (int j = 0; j < 4; ++j)
            up[(long)(vbase + j) * WIN_ + w] = __float2bfloat16(acc[f][j]);
    }
}

// ------- slab(0) from q_buf: slab[by][b][n] = [h|c]_by-slice @ Wsl[by]^T -------
__global__ void __launch_bounds__(256) k_slab0(const bf16* __restrict__ q_buf,
                     const bf16* __restrict__ Wsl, float* __restrict__ slab)
{
    int bx = blockIdx.x, by = blockIdx.y;
    int wave = threadIdx.x >> 6, lane = threadIdx.x & 63;
    int r = lane & 15, ko = (lane >> 4) * 8, rj = (lane >> 4) * 4;
    int m0 = bx * 16;
    const short* qp = (const short*)q_buf;
    const short* wp = (const short*)Wsl + (long)by * NSLN * 128;
    #pragma unroll
    for (int i = 0; i < 5; ++i) {
        int n0 = (wave * 5 + i) * 16;
        f32x4 acc = {};
        #pragma unroll
        for (int k0 = 0; k0 < 128; k0 += 32) {
            long koff = (k0 < 64) ? (by * 64 + k0) : (512 + by * 64 + (k0 - 64));
            bf16x8 a  = *(const bf16x8*)(qp + (long)(m0 + r) * K2H + koff + ko);
            bf16x8 bb = *(const bf16x8*)(wp + (long)(n0 + r) * 128 + k0 + ko);
            acc = __builtin_amdgcn_mfma_f32_16x16x32_bf16(a, bb, acc, 0, 0, 0);
        }
        int n = n0 + r;
        #pragma unroll
        for (int j = 0; j < 4; ++j)
            slab[((long)by * B_ + m0 + rj + j) * NSLN + n] = acc[j];
    }
}

// ---------------- attention: 512 threads, 1 batch per block ----------------
// x (ctx operand) preloaded to registers at entry: both memory streams in
// flight concurrently; x latency hides under score+softmax.
__global__ void __launch_bounds__(512, 4) k_att(
    const bf16* __restrict__ x_bf, const bf16* __restrict__ Uk,
    const float* __restrict__ slab, const float* __restrict__ V,
    const float* __restrict__ bd, bf16* __restrict__ A_cur,
    float* __restrict__ out_y, float* __restrict__ out_w, int s)
{
    __shared__ float v_s[D_];
    __shared__ float wq_s[D_];
    __shared__ float part[32][136];
    __shared__ float att_s[WIN_];
    __shared__ float cpart[16][264];
    __shared__ float redw[4];

    const int b = blockIdx.x;
    const int t = threadIdx.x;
    const int lane = t & 63;

    // ---- issue ctx x loads immediately (no dependencies) ----
    const int dg = t & 31, wg = t >> 5;
    uint4 xu[8];
    {
        const uint4* xp = (const uint4*)((const short*)x_bf + (long)b * (WIN_ * D_));
        #pragma unroll
        for (int i = 0; i < 8; ++i)
            xu[i] = xp[(long)(wg * 8 + i) * 32 + dg];
    }

    if (t < D_) {
        v_s[t] = V[t];
        float wsum = 0.f;                    // Wq[b][t] = sum_by slab[by][b][t]
        #pragma unroll
        for (int by = 0; by < 8; ++by)
            wsum += slab[((long)by * B_ + b) * NSLN + t];
        wq_s[t] = wsum;
    } else if (t < D_ + O_) {                // y(s-1)[b][o] on threads 256..319
        int o = t - D_;
        if (s > 0) {
            float yv = bd[o];
            #pragma unroll
            for (int by = 0; by < 8; ++by)
                yv += slab[((long)by * B_ + b) * NSLN + 256 + o];
            out_y[((long)b * P_ + (s - 1)) * O_ + o] = yv;
            A_cur[(long)b * KG + o] = __float2bfloat16(yv);
        } else {
            A_cur[(long)b * KG + o] = __float2bfloat16(0.f);
        }
    }
    __syncthreads();

    {   // score: thread = (w16 0..15 -> 8 w's, vg 0..31 -> 8 v rows)
        const int w16 = t & 15, vg = t >> 4;
        const uint4* ukp = (const uint4*)((const short*)Uk + (long)b * (D_ * WIN_));
        uint4 u[8];
        #pragma unroll
        for (int i = 0; i < 8; ++i)
            u[i] = ukp[(long)(vg * 8 + i) * 16 + w16];
        float scv[8] = {0.f,0.f,0.f,0.f,0.f,0.f,0.f,0.f};
        #pragma unroll
        for (int i = 0; i < 8; ++i) {
            int v = vg * 8 + i;
            float wqv = wq_s[v], vv = v_s[v];
            scv[0] += vv * fast_tanh(wqv + b_lo(u[i].x));
            scv[1] += vv * fast_tanh(wqv + b_hi(u[i].x));
            scv[2] += vv * fast_tanh(wqv + b_lo(u[i].y));
            scv[3] += vv * fast_tanh(wqv + b_hi(u[i].y));
            scv[4] += vv * fast_tanh(wqv + b_lo(u[i].z));
            scv[5] += vv * fast_tanh(wqv + b_hi(u[i].z));
            scv[6] += vv * fast_tanh(wqv + b_lo(u[i].w));
            scv[7] += vv * fast_tanh(wqv + b_hi(u[i].w));
        }
        #pragma unroll
        for (int j = 0; j < 8; ++j) part[vg][w16 * 8 + j] = scv[j];
    }
    __syncthreads();

    float e = 0.f, scw = 0.f;
    if (t < WIN_) {
        #pragma unroll
        for (int q = 0; q < 32; ++q) scw += part[q][t];
        float m = scw;
        #pragma unroll
        for (int off = 32; off > 0; off >>= 1) m = fmaxf(m, __shfl_xor(m, off));
        if (lane == 0) redw[t >> 6] = m;
    }
    __syncthreads();
    if (t < WIN_) {
        float m = fmaxf(redw[0], redw[1]);
        e = __expf(scw - m);
        float l = e;
        #pragma unroll
        for (int off = 32; off > 0; off >>= 1) l += __shfl_xor(l, off);
        if (lane == 0) redw[2 + (t >> 6)] = l;
    }
    __syncthreads();
    if (t < WIN_) {
        float a = __fdividef(e, redw[2] + redw[3]);
        att_s[t] = a;
        out_w[((long)b * P_ + s) * WIN_ + t] = a;
    }
    __syncthreads();

    {   // ctx: uses preloaded xu; thread = (dg -> 8 d's, wg -> 8 w rows)
        float cacc[8] = {0.f,0.f,0.f,0.f,0.f,0.f,0.f,0.f};
        #pragma unroll
        for (int i = 0; i < 8; ++i) {
            float a = att_s[wg * 8 + i];
            cacc[0] += a * b_lo(xu[i].x);
            cacc[1] += a * b_hi(xu[i].x);
            cacc[2] += a * b_lo(xu[i].y);
            cacc[3] += a * b_hi(xu[i].y);
            cacc[4] += a * b_lo(xu[i].z);
            cacc[5] += a * b_hi(xu[i].z);
            cacc[6] += a * b_lo(xu[i].w);
            cacc[7] += a * b_hi(xu[i].w);
        }
        #pragma unroll
        for (int j = 0; j < 8; ++j) cpart[wg][dg * 8 + j] = cacc[j];
    }
    __syncthreads();
    if (t < 128) {
        int d = t * 2;
        float f0 = 0.f, f1 = 0.f;
        #pragma unroll
        for (int q = 0; q < 16; ++q) { f0 += cpart[q][d]; f1 += cpart[q][d + 1]; }
        *(unsigned int*)(A_cur + (long)b * KG + O_ + d) = pack2(f0, f1);
    }
}

// ------- gates GEMM + LSTM + slab partials, 512 thr, K-split across wave-halves
// grid (32, 8): bx = 16-batch tile, by = 64-j slice (x4 gates)
// waves 0-3: K=[0,416) ; waves 4-7: K=[416,832) -> LDS combine -> LSTM on 0-3
__global__ void __launch_bounds__(512) k_gates(const bf16* __restrict__ A_in,
                     const bf16* __restrict__ Wcomb, const bf16* __restrict__ Wsl,
                     const float* __restrict__ bsum, float* __restrict__ c_f32,
                     bf16* __restrict__ A_out, float* __restrict__ slab)
{
    __shared__ short lhc[16][136];          // [batch][64 h | 64 c], +8 pad
    __shared__ float pacc[4][4][64][4];     // [w4][gate][lane][j] second-half partials
    int bx = blockIdx.x, by = blockIdx.y;
    int wave = threadIdx.x >> 6, lane = threadIdx.x & 63;
    int w4 = wave & 3, half = wave >> 2;
    int r = lane & 15, ko = (lane >> 4) * 8, rj = (lane >> 4) * 4;
    int m0 = bx * 16;
    int jw = by * 64 + w4 * 16;
    const short* ap = (const short*)A_in;
    const short* wp = (const short*)Wcomb;
    f32x4 acc[4] = {};
    long arow = (long)(m0 + r) * KG;
    const int kbeg = half * 416;
    #pragma unroll 2
    for (int kk = 0; kk < 416; kk += 32) {
        int k0 = kbeg + kk;
        bf16x8 a = *(const bf16x8*)(ap + arow + k0 + ko);
        #pragma unroll
        for (int g = 0; g < 4; ++g) {
            bf16x8 bb = *(const bf16x8*)(wp + (long)(g * H_ + jw + r) * KG + k0 + ko);
            acc[g] = __builtin_amdgcn_mfma_f32_16x16x32_bf16(a, bb, acc[g], 0, 0, 0);
        }
    }
    if (half == 1) {
        #pragma unroll
        for (int g = 0; g < 4; ++g)
            #pragma unroll
            for (int j = 0; j < 4; ++j)
                pacc[w4][g][lane][j] = acc[g][j];
    }
    __syncthreads();
    if (half == 0) {
        int jj = jw + r;
        float bi = bsum[jj], bf_ = bsum[H_ + jj];
        float bg = bsum[2*H_ + jj], bo = bsum[3*H_ + jj];
        #pragma unroll
        for (int j = 0; j < 4; ++j) {
            int b = m0 + rj + j;
            float iv = acc[0][j] + pacc[w4][0][lane][j] + bi;
            float fv = acc[1][j] + pacc[w4][1][lane][j] + bf_;
            float gv = acc[2][j] + pacc[w4][2][lane][j] + bg;
            float ov = acc[3][j] + pacc[w4][3][lane][j] + bo;
            float c_old = c_f32[(long)b * H_ + jj];
            float cn = fast_sig(fv) * c_old + fast_sig(iv) * fast_tanh(gv);
            float hn = fast_sig(ov) * fast_tanh(cn);
            c_f32[(long)b * H_ + jj] = cn;
            short hb = f2bs(hn);
            A_out[(long)b * KG + 320 + jj] = __builtin_bit_cast(bf16, (unsigned short)hb);
            lhc[rj + j][w4 * 16 + r]      = hb;
            lhc[rj + j][64 + w4 * 16 + r] = f2bs(cn);
        }
    }
    __syncthreads();
    // slab partial: P(16x320) = lhc(16x128) @ Wsl[by]^T ; 20 tiles over 8 waves
    const short* wsl = (const short*)Wsl + (long)by * NSLN * 128;
    for (int tile = wave; tile < 20; tile += 8) {
        int n0 = tile * 16;
        f32x4 pac = {};
        #pragma unroll
        for (int k0 = 0; k0 < 128; k0 += 32) {
            bf16x8 a  = *(const bf16x8*)(&lhc[r][k0 + ko]);
            bf16x8 bb = *(const bf16x8*)(wsl + (long)(n0 + r) * 128 + k0 + ko);
            pac = __builtin_amdgcn_mfma_f32_16x16x32_bf16(a, bb, pac, 0, 0, 0);
        }
        int n = n0 + r;
        #pragma unroll
        for (int j = 0; j < 4; ++j)
            slab[((long)by * B_ + m0 + rj + j) * NSLN + n] = pac[j];
    }
}

// ---------------- final y (step 63) from slab(64) ----------------
__global__ void __launch_bounds__(256) k_yfin(const float* __restrict__ slab,
                     const float* __restrict__ bd, float* __restrict__ out_y)
{
    int b = blockIdx.x * 4 + (threadIdx.x >> 6);
    int o = threadIdx.x & 63;
    float yv = bd[o];
    #pragma unroll
    for (int by = 0; by < 8; ++by)
        yv += slab[((long)by * B_ + b) * NSLN + 256 + o];
    out_y[((long)b * P_ + 63) * O_ + o] = yv;
}

// ---------------------------------------------------------------------------
extern "C" void kernel_launch(void* const* d_in, const int* in_sizes, int n_in,
                              void* d_out, int out_size, void* d_ws, size_t ws_size,
                              hipStream_t stream)
{
    const float* x    = (const float*)d_in[0];
    const float* V    = (const float*)d_in[1];
    const float* W    = (const float*)d_in[2];
    const float* U    = (const float*)d_in[3];
    const float* W_ih = (const float*)d_in[4];
    const float* W_hh = (const float*)d_in[5];
    const float* b_ih = (const float*)d_in[6];
    const float* b_hh = (const float*)d_in[7];
    const float* Wd   = (const float*)d_in[8];
    const float* bd   = (const float*)d_in[9];
    const float* Ws   = (const float*)d_in[10];
    const float* bs   = (const float*)d_in[11];
    const float* Wc   = (const float*)d_in[12];
    const float* bc   = (const float*)d_in[13];

    float* out_y = (float*)d_out;                         // (512,64,64)
    float* out_w = (float*)d_out + (long)B_ * P_ * O_;    // (512,64,128)

    char* p = (char*)d_ws;
    auto alloc = [&](size_t bytes) { char* r = p; p += (bytes + 255) & ~(size_t)255; return r; };
    bf16*  x_bf  = (bf16*) alloc((size_t)B_ * WIN_ * D_ * 2);   // 33.5 MB
    bf16*  Uk    = (bf16*) alloc((size_t)B_ * D_ * WIN_ * 2);   // 33.5 MB
    bf16*  q_buf = (bf16*) alloc((size_t)B_ * K2H * 2);         // 1 MB
    bf16*  A0    = (bf16*) alloc((size_t)B_ * KG * 2);          // 852 KB
    bf16*  A1    = (bf16*) alloc((size_t)B_ * KG * 2);          // 852 KB
    float* c_f32 = (float*)alloc((size_t)B_ * H_ * 4);          // 1 MB
    float* slab  = (float*)alloc((size_t)8 * B_ * NSLN * 4);    // 5.24 MB
    bf16*  Wcomb = (bf16*) alloc((size_t)NG * KG * 2);          // 3.3 MB
    bf16*  Wsl   = (bf16*) alloc((size_t)8 * NSLN * 128 * 2);   // 655 KB
    bf16*  U_bf  = (bf16*) alloc((size_t)D_ * D_ * 2);          // 128 KB
    bf16*  Wsc   = (bf16*) alloc((size_t)K2H * D_ * 2);         // 512 KB
    float* bsum  = (float*)alloc((size_t)NG * 4);               // 8 KB
    bf16*  Abuf[2] = { A0, A1 };

    k_prep<<<8192, 256, 0, stream>>>(x, W, U, W_ih, W_hh, b_ih, b_hh, Wd, Ws, Wc,
                                     x_bf, Wcomb, Wsl, U_bf, Wsc, bsum);
    k_init2<<<dim3(32, 16), 256, 0, stream>>>(x_bf, Wsc, bs, bc, q_buf, A0, c_f32);
    k_uk<<<dim3(8, 512), 256, 0, stream>>>(U_bf, x_bf, Uk);
    k_slab0<<<dim3(32, 8), 256, 0, stream>>>(q_buf, Wsl, slab);

    for (int s = 0; s < P_; ++s) {
        k_att<<<512, 512, 0, stream>>>(x_bf, Uk, slab, V, bd,
                                       Abuf[s & 1], out_y, out_w, s);
        k_gates<<<dim3(32, 8), 512, 0, stream>>>(Abuf[s & 1], Wcomb, Wsl, bsum,
                                                 c_f32, Abuf[(s + 1) & 1], slab);
    }
    k_yfin<<<128, 256, 0, stream>>>(slab, bd, out_y);
}

// Round 14
// 2348.976 us; speedup vs baseline: 1.1110x; 1.1110x over previous
//
#include <hip/hip_runtime.h>
#include <hip/hip_bf16.h>

// Problem dims
#define B_   512
#define WIN_ 128
#define D_   256
#define H_   512
#define O_   64
#define P_   64
#define K2H  1024   // 2H (q = [h|c])
#define KG   832    // gates GEMM K = O(64) + D(256) + H(512)
#define NG   2048   // 4*H gate dims
#define NSLN 320    // slab N: 256 (Wq) + 64 (y)

typedef __attribute__((ext_vector_type(8))) short bf16x8;
typedef __attribute__((ext_vector_type(4))) float f32x4;
using bf16 = __hip_bfloat16;

__device__ __forceinline__ float fast_tanh(float x){
    float e = __expf(2.f * x);
    return 1.f - __fdividef(2.f, e + 1.f);
}
__device__ __forceinline__ float fast_sig(float x){
    return __fdividef(1.f, 1.f + __expf(-x));
}
__device__ __forceinline__ float b_lo(unsigned int u){ return __uint_as_float(u << 16); }
__device__ __forceinline__ float b_hi(unsigned int u){ return __uint_as_float(u & 0xffff0000u); }
__device__ __forceinline__ short f2bs(float v){
    return (short)__builtin_bit_cast(unsigned short, __float2bfloat16(v));
}
__device__ __forceinline__ unsigned int pack2(float a, float b){
    unsigned short sa = __builtin_bit_cast(unsigned short, __float2bfloat16(a));
    unsigned short sb = __builtin_bit_cast(unsigned short, __float2bfloat16(b));
    return (unsigned int)sa | ((unsigned int)sb << 16);
}

// ---------------- prep: dtype conversions + weight packing ----------------
__global__ void k_prep(const float* __restrict__ x, const float* __restrict__ W,
                       const float* __restrict__ U, const float* __restrict__ W_ih,
                       const float* __restrict__ W_hh, const float* __restrict__ b_ih,
                       const float* __restrict__ b_hh, const float* __restrict__ Wd,
                       const float* __restrict__ Ws, const float* __restrict__ Wc,
                       bf16* __restrict__ x_bf, bf16* __restrict__ Wcomb,
                       bf16* __restrict__ Wsl, bf16* __restrict__ U_bf,
                       bf16* __restrict__ Wsc, float* __restrict__ bsum)
{
    const long NXv = (long)B_ * WIN_ * D_ / 8;    // vectorized x: 8 floats each
    const long NWC = (long)NG * KG;
    const long NSL = (long)8 * NSLN * 128;
    const long NU  = (long)D_ * D_;
    const long NWS = (long)K2H * D_;
    const long NB  = NG;
    const long total = NXv + NWC + NSL + NU + NWS + NB;
    for (long i = (long)blockIdx.x * blockDim.x + threadIdx.x; i < total;
         i += (long)gridDim.x * blockDim.x) {
        long j = i;
        if (j < NXv) {
            const float4* xp = (const float4*)x + j * 2;
            float4 a = xp[0], b = xp[1];
            bf16x8 v;
            v[0] = f2bs(a.x); v[1] = f2bs(a.y); v[2] = f2bs(a.z); v[3] = f2bs(a.w);
            v[4] = f2bs(b.x); v[5] = f2bs(b.y); v[6] = f2bs(b.z); v[7] = f2bs(b.w);
            *(bf16x8*)((short*)x_bf + j * 8) = v;
            continue;
        }
        j -= NXv;
        if (j < NWC) {      // [W_ih | W_hh] packed K=832
            long n = j / KG, k = j % KG;
            float v = (k < 320) ? W_ih[n * 320 + k] : W_hh[n * 512 + (k - 320)];
            Wcomb[j] = __float2bfloat16(v); continue;
        }
        j -= NWC;
        if (j < NSL) {      // K-slice 'by' of [W ; Wd] for slab partials
            long by = j / (NSLN * 128);
            long rem = j % (NSLN * 128);
            long n = rem / 128, k = rem % 128;
            float v;
            if (n < 256) v = (k < 64) ? W[n * K2H + by * 64 + k]
                                      : W[n * K2H + 512 + by * 64 + (k - 64)];
            else         v = (k < 64) ? Wd[(n - 256) * H_ + by * 64 + k] : 0.f;
            Wsl[j] = __float2bfloat16(v); continue;
        }
        j -= NSL;
        if (j < NU) { U_bf[j] = __float2bfloat16(U[j]); continue; }
        j -= NU;
        if (j < NWS) {      // [Ws;Wc]
            long n = j / D_, k = j % D_;
            float v = (n < 512) ? Ws[n * D_ + k] : Wc[(n - 512) * D_ + k];
            Wsc[j] = __float2bfloat16(v); continue;
        }
        j -= NWS;
        bsum[j] = b_ih[j] + b_hh[j];
    }
}

// ------- init (MFMA): x_last(512x256) @ Wsc^T(1024x256) -> h0 | c0 ---------
__global__ void __launch_bounds__(256) k_init2(const bf16* __restrict__ x_bf,
                       const bf16* __restrict__ Wsc, const float* __restrict__ bs,
                       const float* __restrict__ bc, bf16* __restrict__ q_buf,
                       bf16* __restrict__ A0, float* __restrict__ c_f32)
{
    int wave = threadIdx.x >> 6, lane = threadIdx.x & 63;
    int m0 = blockIdx.x * 16;
    int n0 = blockIdx.y * 64 + wave * 16;
    int r = lane & 15, ko = (lane >> 4) * 8, rj = (lane >> 4) * 4;
    const short* xp = (const short*)x_bf;
    const short* wp = (const short*)Wsc;
    f32x4 acc = {};
    #pragma unroll
    for (int k0 = 0; k0 < D_; k0 += 32) {
        bf16x8 a  = *(const bf16x8*)(xp + (long)(m0 + r) * (WIN_ * D_) + 127 * D_ + k0 + ko);
        bf16x8 bb = *(const bf16x8*)(wp + (long)(n0 + r) * D_ + k0 + ko);
        acc = __builtin_amdgcn_mfma_f32_16x16x32_bf16(a, bb, acc, 0, 0, 0);
    }
    int n = n0 + r;
    if (n0 < 512) {          // h0
        float bias = bs[n];
        #pragma unroll
        for (int j = 0; j < 4; ++j) {
            int b = m0 + rj + j;
            float hv = fast_tanh(acc[j] + bias);
            bf16 hb = __float2bfloat16(hv);
            q_buf[(long)b * K2H + n]   = hb;
            A0[(long)b * KG + 320 + n] = hb;
        }
    } else {                 // c0
        float bias = bc[n - 512];
        #pragma unroll
        for (int j = 0; j < 4; ++j) {
            int b = m0 + rj + j;
            float cv = fast_sig(acc[j] + bias);
            q_buf[(long)b * K2H + n]        = __float2bfloat16(cv);
            c_f32[(long)b * H_ + (n - 512)] = cv;
        }
    }
}

// ---------------- Uk[b] = U @ x[b]^T  (x-tile staged in LDS) ----------------
__global__ void __launch_bounds__(256) k_uk(const bf16* __restrict__ U_bf,
                    const bf16* __restrict__ x_bf, bf16* __restrict__ Uk)
{
    __shared__ __align__(16) short xs[64][264];
    int b  = blockIdx.y;
    int v0 = (blockIdx.x >> 1) * 64;
    int w0 = (blockIdx.x & 1) * 64;
    {   // stage x rows w0..w0+63 ; 64B-contiguous per 4 lanes, spread banks
        const short* xg = (const short*)x_bf + (long)b * (WIN_ * D_) + (long)w0 * D_;
        int row = threadIdx.x >> 2, c4 = (threadIdx.x & 3) * 8;
        #pragma unroll
        for (int i = 0; i < 8; ++i)
            *(bf16x8*)(&xs[row][c4 + i * 32]) = *(const bf16x8*)(xg + (long)row * D_ + c4 + i * 32);
    }
    __syncthreads();
    int lane = threadIdx.x & 63;
    int wave = threadIdx.x >> 6;
    int r  = lane & 15;
    int ko = (lane >> 4) * 8;
    const short* Up = (const short*)U_bf + (long)(v0 + wave * 16 + r) * D_;
    f32x4 acc[4] = {};
    #pragma unroll 2
    for (int k0 = 0; k0 < D_; k0 += 32) {
        bf16x8 a = *(const bf16x8*)(Up + k0 + ko);
        #pragma unroll
        for (int f = 0; f < 4; ++f) {
            bf16x8 bb = *(const bf16x8*)(&xs[f * 16 + r][k0 + ko]);
            acc[f] = __builtin_amdgcn_mfma_f32_16x16x32_bf16(a, bb, acc[f], 0, 0, 0);
        }
    }
    bf16* up = Uk + (long)b * (D_ * WIN_);
    int vbase = v0 + wave * 16 + (lane >> 4) * 4;
    #pragma unroll
    for (int f = 0; f < 4; ++f) {
        int w = w0 + f * 16 + r;
        #pragma unroll
        for (int j = 0; j < 4; ++j)
            up[(long)(vbase + j) * WIN_ + w] = __float2bfloat16(acc[f][j]);
    }
}

// ------- slab(0) from q_buf: slab[by][b][n] = [h|c]_by-slice @ Wsl[by]^T -------
__global__ void __launch_bounds__(256) k_slab0(const bf16* __restrict__ q_buf,
                     const bf16* __restrict__ Wsl, float* __restrict__ slab)
{
    int bx = blockIdx.x, by = blockIdx.y;
    int wave = threadIdx.x >> 6, lane = threadIdx.x & 63;
    int r = lane & 15, ko = (lane >> 4) * 8, rj = (lane >> 4) * 4;
    int m0 = bx * 16;
    const short* qp = (const short*)q_buf;
    const short* wp = (const short*)Wsl + (long)by * NSLN * 128;
    #pragma unroll
    for (int i = 0; i < 5; ++i) {
        int n0 = (wave * 5 + i) * 16;
        f32x4 acc = {};
        #pragma unroll
        for (int k0 = 0; k0 < 128; k0 += 32) {
            long koff = (k0 < 64) ? (by * 64 + k0) : (512 + by * 64 + (k0 - 64));
            bf16x8 a  = *(const bf16x8*)(qp + (long)(m0 + r) * K2H + koff + ko);
            bf16x8 bb = *(const bf16x8*)(wp + (long)(n0 + r) * 128 + k0 + ko);
            acc = __builtin_amdgcn_mfma_f32_16x16x32_bf16(a, bb, acc, 0, 0, 0);
        }
        int n = n0 + r;
        #pragma unroll
        for (int j = 0; j < 4; ++j)
            slab[((long)by * B_ + m0 + rj + j) * NSLN + n] = acc[j];
    }
}

// ---------------- attention: 512 threads, 1 batch per block ----------------
// 2 blocks/CU = 16 waves/CU (50% occupancy) -> 2x in-flight bytes vs 256-thr
__global__ void __launch_bounds__(512) k_att(
    const bf16* __restrict__ x_bf, const bf16* __restrict__ Uk,
    const float* __restrict__ slab, const float* __restrict__ V,
    const float* __restrict__ bd, bf16* __restrict__ A_cur,
    float* __restrict__ out_y, float* __restrict__ out_w, int s)
{
    __shared__ float v_s[D_];
    __shared__ float wq_s[D_];
    __shared__ float part[32][136];
    __shared__ float att_s[WIN_];
    __shared__ float cpart[16][264];
    __shared__ float redw[4];

    const int b = blockIdx.x;
    const int t = threadIdx.x;
    const int lane = t & 63;

    if (t < D_) {
        v_s[t] = V[t];
        float wsum = 0.f;                    // Wq[b][t] = sum_by slab[by][b][t]
        #pragma unroll
        for (int by = 0; by < 8; ++by)
            wsum += slab[((long)by * B_ + b) * NSLN + t];
        wq_s[t] = wsum;
    } else if (t < D_ + O_) {                // y(s-1)[b][o] on threads 256..319
        int o = t - D_;
        if (s > 0) {
            float yv = bd[o];
            #pragma unroll
            for (int by = 0; by < 8; ++by)
                yv += slab[((long)by * B_ + b) * NSLN + 256 + o];
            out_y[((long)b * P_ + (s - 1)) * O_ + o] = yv;
            A_cur[(long)b * KG + o] = __float2bfloat16(yv);
        } else {
            A_cur[(long)b * KG + o] = __float2bfloat16(0.f);
        }
    }
    __syncthreads();

    {   // score: thread = (w16 0..15 -> 8 w's, vg 0..31 -> 8 v rows)
        const int w16 = t & 15, vg = t >> 4;
        const uint4* ukp = (const uint4*)((const short*)Uk + (long)b * (D_ * WIN_));
        uint4 u[8];
        #pragma unroll
        for (int i = 0; i < 8; ++i)
            u[i] = ukp[(long)(vg * 8 + i) * 16 + w16];
        float scv[8] = {0.f,0.f,0.f,0.f,0.f,0.f,0.f,0.f};
        #pragma unroll
        for (int i = 0; i < 8; ++i) {
            int v = vg * 8 + i;
            float wqv = wq_s[v], vv = v_s[v];
            scv[0] += vv * fast_tanh(wqv + b_lo(u[i].x));
            scv[1] += vv * fast_tanh(wqv + b_hi(u[i].x));
            scv[2] += vv * fast_tanh(wqv + b_lo(u[i].y));
            scv[3] += vv * fast_tanh(wqv + b_hi(u[i].y));
            scv[4] += vv * fast_tanh(wqv + b_lo(u[i].z));
            scv[5] += vv * fast_tanh(wqv + b_hi(u[i].z));
            scv[6] += vv * fast_tanh(wqv + b_lo(u[i].w));
            scv[7] += vv * fast_tanh(wqv + b_hi(u[i].w));
        }
        #pragma unroll
        for (int j = 0; j < 8; ++j) part[vg][w16 * 8 + j] = scv[j];
    }
    __syncthreads();

    float e = 0.f, scw = 0.f;
    if (t < WIN_) {
        #pragma unroll
        for (int q = 0; q < 32; ++q) scw += part[q][t];
        float m = scw;
        #pragma unroll
        for (int off = 32; off > 0; off >>= 1) m = fmaxf(m, __shfl_xor(m, off));
        if (lane == 0) redw[t >> 6] = m;
    }
    __syncthreads();
    if (t < WIN_) {
        float m = fmaxf(redw[0], redw[1]);
        e = __expf(scw - m);
        float l = e;
        #pragma unroll
        for (int off = 32; off > 0; off >>= 1) l += __shfl_xor(l, off);
        if (lane == 0) redw[2 + (t >> 6)] = l;
    }
    __syncthreads();
    if (t < WIN_) {
        float a = __fdividef(e, redw[2] + redw[3]);
        att_s[t] = a;
        out_w[((long)b * P_ + s) * WIN_ + t] = a;
    }
    __syncthreads();

    {   // ctx: thread = (dg 0..31 -> 8 d's, wg 0..15 -> 8 w rows)
        const int dg = t & 31, wg = t >> 5;
        const uint4* xp = (const uint4*)((const short*)x_bf + (long)b * (WIN_ * D_));
        uint4 u[8];
        #pragma unroll
        for (int i = 0; i < 8; ++i)
            u[i] = xp[(long)(wg * 8 + i) * 32 + dg];
        float cacc[8] = {0.f,0.f,0.f,0.f,0.f,0.f,0.f,0.f};
        #pragma unroll
        for (int i = 0; i < 8; ++i) {
            float a = att_s[wg * 8 + i];
            cacc[0] += a * b_lo(u[i].x);
            cacc[1] += a * b_hi(u[i].x);
            cacc[2] += a * b_lo(u[i].y);
            cacc[3] += a * b_hi(u[i].y);
            cacc[4] += a * b_lo(u[i].z);
            cacc[5] += a * b_hi(u[i].z);
            cacc[6] += a * b_lo(u[i].w);
            cacc[7] += a * b_hi(u[i].w);
        }
        #pragma unroll
        for (int j = 0; j < 8; ++j) cpart[wg][dg * 8 + j] = cacc[j];
    }
    __syncthreads();
    if (t < 128) {
        int d = t * 2;
        float f0 = 0.f, f1 = 0.f;
        #pragma unroll
        for (int q = 0; q < 16; ++q) { f0 += cpart[q][d]; f1 += cpart[q][d + 1]; }
        *(unsigned int*)(A_cur + (long)b * KG + O_ + d) = pack2(f0, f1);
    }
}

// ------- gates GEMM + LSTM + slab partials (Wq/y lookahead) -------
// grid (32, 8) x 256 thr: bx = 16-batch tile, by = 64-j slice (x4 gates)
__global__ void __launch_bounds__(256) k_gates(const bf16* __restrict__ A_in,
                     const bf16* __restrict__ Wcomb, const bf16* __restrict__ Wsl,
                     const float* __restrict__ bsum, float* __restrict__ c_f32,
                     bf16* __restrict__ A_out, float* __restrict__ slab)
{
    __shared__ short lhc[16][136];   // [batch][64 h | 64 c], +8 pad
    int bx = blockIdx.x, by = blockIdx.y;
    int wave = threadIdx.x >> 6, lane = threadIdx.x & 63;
    int r = lane & 15, ko = (lane >> 4) * 8, rj = (lane >> 4) * 4;
    int m0 = bx * 16;
    int jw = by * 64 + wave * 16;
    const short* ap = (const short*)A_in;
    const short* wp = (const short*)Wcomb;
    f32x4 acc[4] = {};
    long arow = (long)(m0 + r) * KG;
    #pragma unroll 2
    for (int k0 = 0; k0 < KG; k0 += 32) {
        bf16x8 a = *(const bf16x8*)(ap + arow + k0 + ko);
        #pragma unroll
        for (int g = 0; g < 4; ++g) {
            bf16x8 bb = *(const bf16x8*)(wp + (long)(g * H_ + jw + r) * KG + k0 + ko);
            acc[g] = __builtin_amdgcn_mfma_f32_16x16x32_bf16(a, bb, acc[g], 0, 0, 0);
        }
    }
    int jj = jw + r;
    float bi = bsum[jj], bf_ = bsum[H_ + jj], bg = bsum[2*H_ + jj], bo = bsum[3*H_ + jj];
    #pragma unroll
    for (int j = 0; j < 4; ++j) {
        int b = m0 + rj + j;
        float iv = acc[0][j] + bi;
        float fv = acc[1][j] + bf_;
        float gv = acc[2][j] + bg;
        float ov = acc[3][j] + bo;
        float c_old = c_f32[(long)b * H_ + jj];
        float cn = fast_sig(fv) * c_old + fast_sig(iv) * fast_tanh(gv);
        float hn = fast_sig(ov) * fast_tanh(cn);
        c_f32[(long)b * H_ + jj] = cn;
        short hb = f2bs(hn);
        A_out[(long)b * KG + 320 + jj] = __builtin_bit_cast(bf16, (unsigned short)hb);
        lhc[rj + j][wave * 16 + r]      = hb;
        lhc[rj + j][64 + wave * 16 + r] = f2bs(cn);
    }
    __syncthreads();
    // slab partial: P(16x320) = lhc(16x128) @ Wsl[by]^T
    const short* wsl = (const short*)Wsl + (long)by * NSLN * 128;
    #pragma unroll
    for (int i = 0; i < 5; ++i) {
        int n0 = (wave * 5 + i) * 16;
        f32x4 pac = {};
        #pragma unroll
        for (int k0 = 0; k0 < 128; k0 += 32) {
            bf16x8 a  = *(const bf16x8*)(&lhc[r][k0 + ko]);
            bf16x8 bb = *(const bf16x8*)(wsl + (long)(n0 + r) * 128 + k0 + ko);
            pac = __builtin_amdgcn_mfma_f32_16x16x32_bf16(a, bb, pac, 0, 0, 0);
        }
        int n = n0 + r;
        #pragma unroll
        for (int j = 0; j < 4; ++j)
            slab[((long)by * B_ + m0 + rj + j) * NSLN + n] = pac[j];
    }
}

// ---------------- final y (step 63) from slab(64) ----------------
__global__ void __launch_bounds__(256) k_yfin(const float* __restrict__ slab,
                     const float* __restrict__ bd, float* __restrict__ out_y)
{
    int b = blockIdx.x * 4 + (threadIdx.x >> 6);
    int o = threadIdx.x & 63;
    float yv = bd[o];
    #pragma unroll
    for (int by = 0; by < 8; ++by)
        yv += slab[((long)by * B_ + b) * NSLN + 256 + o];
    out_y[((long)b * P_ + 63) * O_ + o] = yv;
}

// ---------------------------------------------------------------------------
extern "C" void kernel_launch(void* const* d_in, const int* in_sizes, int n_in,
                              void* d_out, int out_size, void* d_ws, size_t ws_size,
                              hipStream_t stream)
{
    const float* x    = (const float*)d_in[0];
    const float* V    = (const float*)d_in[1];
    const float* W    = (const float*)d_in[2];
    const float* U    = (const float*)d_in[3];
    const float* W_ih = (const float*)d_in[4];
    const float* W_hh = (const float*)d_in[5];
    const float* b_ih = (const float*)d_in[6];
    const float* b_hh = (const float*)d_in[7];
    const float* Wd   = (const float*)d_in[8];
    const float* bd   = (const float*)d_in[9];
    const float* Ws   = (const float*)d_in[10];
    const float* bs   = (const float*)d_in[11];
    const float* Wc   = (const float*)d_in[12];
    const float* bc   = (const float*)d_in[13];

    float* out_y = (float*)d_out;                         // (512,64,64)
    float* out_w = (float*)d_out + (long)B_ * P_ * O_;    // (512,64,128)

    char* p = (char*)d_ws;
    auto alloc = [&](size_t bytes) { char* r = p; p += (bytes + 255) & ~(size_t)255; return r; };
    bf16*  x_bf  = (bf16*) alloc((size_t)B_ * WIN_ * D_ * 2);   // 33.5 MB
    bf16*  Uk    = (bf16*) alloc((size_t)B_ * D_ * WIN_ * 2);   // 33.5 MB
    bf16*  q_buf = (bf16*) alloc((size_t)B_ * K2H * 2);         // 1 MB
    bf16*  A0    = (bf16*) alloc((size_t)B_ * KG * 2);          // 852 KB
    bf16*  A1    = (bf16*) alloc((size_t)B_ * KG * 2);          // 852 KB
    float* c_f32 = (float*)alloc((size_t)B_ * H_ * 4);          // 1 MB
    float* slab  = (float*)alloc((size_t)8 * B_ * NSLN * 4);    // 5.24 MB
    bf16*  Wcomb = (bf16*) alloc((size_t)NG * KG * 2);          // 3.3 MB
    bf16*  Wsl   = (bf16*) alloc((size_t)8 * NSLN * 128 * 2);   // 655 KB
    bf16*  U_bf  = (bf16*) alloc((size_t)D_ * D_ * 2);          // 128 KB
    bf16*  Wsc   = (bf16*) alloc((size_t)K2H * D_ * 2);         // 512 KB
    float* bsum  = (float*)alloc((size_t)NG * 4);               // 8 KB
    bf16*  Abuf[2] = { A0, A1 };

    k_prep<<<8192, 256, 0, stream>>>(x, W, U, W_ih, W_hh, b_ih, b_hh, Wd, Ws, Wc,
                                     x_bf, Wcomb, Wsl, U_bf, Wsc, bsum);
    k_init2<<<dim3(32, 16), 256, 0, stream>>>(x_bf, Wsc, bs, bc, q_buf, A0, c_f32);
    k_uk<<<dim3(8, 512), 256, 0, stream>>>(U_bf, x_bf, Uk);
    k_slab0<<<dim3(32, 8), 256, 0, stream>>>(q_buf, Wsl, slab);

    for (int s = 0; s < P_; ++s) {
        k_att<<<512, 512, 0, stream>>>(x_bf, Uk, slab, V, bd,
                                       Abuf[s & 1], out_y, out_w, s);
        k_gates<<<dim3(32, 8), 256, 0, stream>>>(Abuf[s & 1], Wcomb, Wsl, bsum,
                                                 c_f32, Abuf[(s + 1) & 1], slab);
    }
    k_yfin<<<128, 256, 0, stream>>>(slab, bd, out_y);
}